// Round 4
// baseline (186.173 us; speedup 1.0000x reference)
//
#include <hip/hip_runtime.h>
#include <hip/hip_bf16.h>
#include <math.h>

#define B_ 4
#define T_ 4096
#define E_ 1024
#define H_ 64
#define NQT 128      // T_/32 q-tiles
#define NCH 4        // passA key chunks (1024 keys each)
#define KCHUNK 1024
#define NCHP 8       // passB chunk slots (512 keys each)
#define KCHB 512
#define TILES 576    // per-batch live causal tiles: sum_qt ((qt>>4)+1)

using bf16x8 = __attribute__((ext_vector_type(8))) short;
using f32x4  = __attribute__((ext_vector_type(4))) float;

__device__ inline short f2bf(float f) {
  __hip_bfloat16 h = __float2bfloat16(f);
  return *reinterpret_cast<short*>(&h);
}
__device__ inline float bf2f(short s) {
  unsigned u = ((unsigned)(unsigned short)s) << 16;
  return __builtin_bit_cast(float, u);
}

// ---------- W transpose+convert: wt[mat*64+n][k] = W[k][n] (bf16) ----------
__global__ __launch_bounds__(256)
void wtconv_kernel(const float* __restrict__ wq, const float* __restrict__ wk,
                   const float* __restrict__ wv, short* __restrict__ wt) {
  const int row = blockIdx.x;          // 0..191
  const int mat = row >> 6, n = row & 63;
  const float* W = (mat == 0) ? wq : (mat == 1) ? wk : wv;
  for (int k = threadIdx.x; k < E_; k += 256)
    wt[(size_t)row * E_ + k] = f2bf(W[(size_t)k * H_ + n]);
}

// ---------- QKV projection: single pass over x ----------
// 512 blocks x 4 waves; wave = (qsub of 16 rows, col-half of 96 cols).
__global__ __launch_bounds__(256)
void proj_kernel(const float* __restrict__ x, const short* __restrict__ wt,
                 short* __restrict__ Qb, short* __restrict__ Kb,
                 short* __restrict__ Vt) {
  const int q0 = blockIdx.x * 32;
  const int t = threadIdx.x;
  const int wave = t >> 6, lane = t & 63, g = lane >> 4, l15 = lane & 15;
  const int qsub = wave >> 1, ch = wave & 1;
  const int arow = q0 + qsub * 16 + l15;
  f32x4 acc[6] = {{0,0,0,0},{0,0,0,0},{0,0,0,0},{0,0,0,0},{0,0,0,0},{0,0,0,0}};
#pragma unroll 2
  for (int k0 = 0; k0 < E_; k0 += 32) {
    const float* xp = x + (size_t)arow * E_ + k0 + 8 * g;
    const float4 x0 = *(const float4*)xp;
    const float4 x1 = *(const float4*)(xp + 4);
    bf16x8 av;
    av[0]=f2bf(x0.x); av[1]=f2bf(x0.y); av[2]=f2bf(x0.z); av[3]=f2bf(x0.w);
    av[4]=f2bf(x1.x); av[5]=f2bf(x1.y); av[6]=f2bf(x1.z); av[7]=f2bf(x1.w);
#pragma unroll
    for (int n = 0; n < 6; ++n) {
      const int ntg = ch * 6 + n;
      const bf16x8 bfr = *(const bf16x8*)&wt[(size_t)(ntg*16 + l15) * E_ + k0 + 8*g];
      acc[n] = __builtin_amdgcn_mfma_f32_16x16x32_bf16(av, bfr, acc[n], 0, 0, 0);
    }
  }
#pragma unroll
  for (int n = 0; n < 6; ++n) {
    const int ntg = ch * 6 + n;
    const int mat = ntg >> 2;
    const int h = (ntg & 3) * 16 + l15;
#pragma unroll
    for (int r = 0; r < 4; ++r) {
      const int q = q0 + qsub * 16 + 4 * g + r;
      const short v = f2bf(acc[n][r]);
      if (mat == 0)      Qb[(size_t)q * H_ + h] = v;
      else if (mat == 1) Kb[(size_t)q * H_ + h] = v;
      else               Vt[((size_t)(q >> 12) * H_ + h) * T_ + (q & (T_ - 1))] = v;
    }
  }
}

// ---------- pass A: partial Z over a 1024-key chunk ----------
__global__ __launch_bounds__(256)
void passA_kernel(const short* __restrict__ Qb, const short* __restrict__ Kb,
                  float* __restrict__ Zp) {
  __shared__ float partial[4][32];
  const int qt = blockIdx.x, c = blockIdx.y, b = blockIdx.z;
  const int q0 = qt * 32;
  const int t = threadIdx.x;
  const int wave = t >> 6, lane = t & 63, g = lane >> 4, l15 = lane & 15;
  const short* Qp = Qb + (size_t)b * T_ * H_;
  const short* Kp = Kb + (size_t)b * T_ * H_;
  bf16x8 aq[2][2];
#pragma unroll
  for (int qs = 0; qs < 2; ++qs)
#pragma unroll
    for (int h = 0; h < 2; ++h)
      aq[qs][h] = *(const bf16x8*)&Qp[(size_t)(q0 + qs*16 + l15) * H_ + h*32 + 8*g];
  float z[2][4] = {{0,0,0,0},{0,0,0,0}};
  const int kendc = c * KCHUNK + KCHUNK;
#pragma unroll 2
  for (int kt = c * KCHUNK + wave * 16; kt < kendc; kt += 64) {
    const bf16x8 bk0 = *(const bf16x8*)&Kp[(size_t)(kt + l15) * H_ + 8*g];
    const bf16x8 bk1 = *(const bf16x8*)&Kp[(size_t)(kt + l15) * H_ + 32 + 8*g];
#pragma unroll
    for (int qs = 0; qs < 2; ++qs) {
      f32x4 cc = {0,0,0,0};
      cc = __builtin_amdgcn_mfma_f32_16x16x32_bf16(aq[qs][0], bk0, cc, 0,0,0);
      cc = __builtin_amdgcn_mfma_f32_16x16x32_bf16(aq[qs][1], bk1, cc, 0,0,0);
#pragma unroll
      for (int r = 0; r < 4; ++r) z[qs][r] += __expf(cc[r] * 0.125f);
    }
  }
#pragma unroll
  for (int qs = 0; qs < 2; ++qs)
#pragma unroll
    for (int r = 0; r < 4; ++r) {
      float v = z[qs][r];
      v += __shfl_xor(v, 1); v += __shfl_xor(v, 2);
      v += __shfl_xor(v, 4); v += __shfl_xor(v, 8);
      z[qs][r] = v;
    }
  if (l15 == 0) {
#pragma unroll
    for (int qs = 0; qs < 2; ++qs)
#pragma unroll
      for (int r = 0; r < 4; ++r)
        partial[wave][qs * 16 + 4 * g + r] = z[qs][r];
  }
  __syncthreads();
  if (t < 32)
    Zp[((size_t)(b * NQT + qt) * NCH + c) * 32 + t] =
        partial[0][t] + partial[1][t] + partial[2][t] + partial[3][t];
}

// ---------- pass B: causal chunk partial (w V, sum w) ----------
// Flat live-tile grid (576 per batch), heavy-first; 512-key chunks.
#define WSTRIDE 40
__global__ __launch_bounds__(256)
void passB_kernel(const short* __restrict__ Qb, const short* __restrict__ Kb,
                  const short* __restrict__ Vt, const float* __restrict__ Zp,
                  short* __restrict__ po, float* __restrict__ pws) {
  __shared__ short wtile[4][2][16 * WSTRIDE];
  __shared__ float comb[2][16][68];
  __shared__ float wsum_lds[2][16];
  const int b = blockIdx.y;
  const int f = TILES - 1 - blockIdx.x;    // ascending live-tile index
  int a = 0;
#pragma unroll
  for (int aa = 1; aa <= 7; ++aa) a += (f >= 8 * aa * (aa + 1)) ? 1 : 0;
  const int rem = f - 8 * a * (a + 1);
  const int r_ = rem / (a + 1);
  const int c = rem - r_ * (a + 1);
  const int qt = (a << 4) + r_;
  const int q0 = qt * 32;
  const int c0 = c * KCHB;
  const int kend = min(c0 + KCHB, q0 + 32);

  const int t = threadIdx.x;
  const int wave = t >> 6, lane = t & 63, g = lane >> 4, l15 = lane & 15;
  const int qsub = wave & 1;
  const short* Qp = Qb + (size_t)b * T_ * H_;
  const short* Kp = Kb + (size_t)b * T_ * H_;
  const short* Vp = Vt + (size_t)b * H_ * T_;
  bf16x8 aq[2];
  aq[0] = *(const bf16x8*)&Qp[(size_t)(q0 + qsub*16 + l15) * H_ + 8*g];
  aq[1] = *(const bf16x8*)&Qp[(size_t)(q0 + qsub*16 + l15) * H_ + 32 + 8*g];
  const size_t zbase = (size_t)(b * NQT + qt) * NCH;
  float zinv[4];
#pragma unroll
  for (int r = 0; r < 4; ++r) {
    const int q = qsub * 16 + 4 * g + r;
    float zt = 0.f;
#pragma unroll
    for (int cc = 0; cc < NCH; ++cc) zt += Zp[(zbase + cc) * 32 + q];
    zinv[r] = 1.0f / zt;
  }
  f32x4 o[4] = {{0,0,0,0},{0,0,0,0},{0,0,0,0},{0,0,0,0}};
  float ws[4] = {0,0,0,0};
  const int kbeg = c0 + (wave >> 1) * 32;
  int it = 0;
#pragma unroll 2
  for (int kt = kbeg; kt < kend; kt += 64, ++it) {
    short* wb = wtile[wave][it & 1];
#pragma unroll
    for (int k16 = 0; k16 < 2; ++k16) {
      const bf16x8 bk0 = *(const bf16x8*)&Kp[(size_t)(kt + k16*16 + l15) * H_ + 8*g];
      const bf16x8 bk1 = *(const bf16x8*)&Kp[(size_t)(kt + k16*16 + l15) * H_ + 32 + 8*g];
      f32x4 s = {0,0,0,0};
      s = __builtin_amdgcn_mfma_f32_16x16x32_bf16(aq[0], bk0, s, 0,0,0);
      s = __builtin_amdgcn_mfma_f32_16x16x32_bf16(aq[1], bk1, s, 0,0,0);
      const int kcol = kt + k16 * 16 + l15;
#pragma unroll
      for (int r = 0; r < 4; ++r) {
        const int qglob = q0 + qsub * 16 + 4 * g + r;
        const float p1 = __expf(s[r] * 0.125f) * zinv[r];
        const float w = (kcol <= qglob) ? __expf(p1) : 0.0f;
        ws[r] += w;
        wb[(4 * g + r) * WSTRIDE + k16 * 16 + l15] = f2bf(w);
      }
    }
    const bf16x8 pa = *(const bf16x8*)&wb[l15 * WSTRIDE + 8 * g];
#pragma unroll
    for (int nt = 0; nt < 4; ++nt) {
      const bf16x8 bv = *(const bf16x8*)&Vp[(size_t)(nt*16 + l15) * T_ + kt + 8*g];
      o[nt] = __builtin_amdgcn_mfma_f32_16x16x32_bf16(pa, bv, o[nt], 0,0,0);
    }
  }
#pragma unroll
  for (int r = 0; r < 4; ++r) {
    float v = ws[r];
    v += __shfl_xor(v, 1); v += __shfl_xor(v, 2);
    v += __shfl_xor(v, 4); v += __shfl_xor(v, 8);
    ws[r] = v;
  }
  if (wave >> 1) {
#pragma unroll
    for (int nt = 0; nt < 4; ++nt)
#pragma unroll
      for (int r = 0; r < 4; ++r)
        comb[qsub][4 * g + r][nt * 16 + l15] = o[nt][r];
    if (l15 == 0)
#pragma unroll
      for (int r = 0; r < 4; ++r) wsum_lds[qsub][4 * g + r] = ws[r];
  }
  __syncthreads();
  if (!(wave >> 1)) {
    const size_t idx = (size_t)(b * NQT + qt) * NCHP + c;
#pragma unroll
    for (int r = 0; r < 4; ++r) {
      const size_t row = idx * 32 + qsub * 16 + 4 * g + r;
#pragma unroll
      for (int nt = 0; nt < 4; ++nt)
        po[row * 64 + nt * 16 + l15] =
            f2bf(o[nt][r] + comb[qsub][4 * g + r][nt * 16 + l15]);
    }
    if (l15 == 0)
#pragma unroll
      for (int r = 0; r < 4; ++r)
        pws[idx * 32 + qsub * 16 + 4 * g + r] =
            ws[r] + wsum_lds[qsub][4 * g + r];
  }
}

// ---------- combine: out = sum_c po / sum_c pws ----------
__global__ __launch_bounds__(256)
void combine_kernel(const short* __restrict__ po, const float* __restrict__ pws,
                    float* __restrict__ out) {
  const int qt = blockIdx.x, b = blockIdx.y;
  const int nc = (qt >> 4) + 1;
  const size_t base = (size_t)(b * NQT + qt) * NCHP;
  for (int e = threadIdx.x; e < 512; e += 256) {
    const int q = e >> 4, d4 = e & 15;
    float ax = 0.f, ay = 0.f, az = 0.f, aw = 0.f, wsr = 0.f;
    for (int cc = 0; cc < nc; ++cc) {
      const short4 v = *(const short4*)&po[((base + cc) * 32 + q) * 64 + d4 * 4];
      ax += bf2f(v.x); ay += bf2f(v.y); az += bf2f(v.z); aw += bf2f(v.w);
      wsr += pws[(base + cc) * 32 + q];
    }
    const float inv = 1.0f / wsr;
    float4 rv = make_float4(ax * inv, ay * inv, az * inv, aw * inv);
    *(float4*)&out[((size_t)(b * T_ + qt * 32 + q)) * H_ + d4 * 4] = rv;
  }
}

extern "C" void kernel_launch(void* const* d_in, const int* in_sizes, int n_in,
                              void* d_out, int out_size, void* d_ws, size_t ws_size,
                              hipStream_t stream) {
  (void)in_sizes; (void)n_in; (void)out_size; (void)ws_size;
  const float* x  = (const float*)d_in[0];
  const float* wq = (const float*)d_in[1];
  const float* wk = (const float*)d_in[2];
  const float* wv = (const float*)d_in[3];

  char* ws = (char*)d_ws;
  short* wt  = (short*)(ws);                       // 384 KB
  short* Qb  = (short*)(ws + 0x0060000);           // 2 MB
  short* Kb  = (short*)(ws + 0x0260000);           // 2 MB
  short* Vt  = (short*)(ws + 0x0460000);           // 2 MB
  float* Zp  = (float*)(ws + 0x0660000);           // 256 KB
  float* pws = (float*)(ws + 0x06A0000);           // 512 KB
  short* po  = (short*)(ws + 0x0720000);           // 16 MB bf16
  float* outp = (float*)d_out;

  wtconv_kernel<<<192, 256, 0, stream>>>(wq, wk, wv, wt);
  proj_kernel<<<(B_ * T_) / 32, 256, 0, stream>>>(x, wt, Qb, Kb, Vt);
  passA_kernel<<<dim3(NQT, NCH, B_), 256, 0, stream>>>(Qb, Kb, Zp);
  passB_kernel<<<dim3(TILES, B_), 256, 0, stream>>>(Qb, Kb, Vt, Zp, po, pws);
  combine_kernel<<<dim3(NQT, B_), 256, 0, stream>>>(po, pws, outp);
}

// Round 5
// 180.901 us; speedup vs baseline: 1.0291x; 1.0291x over previous
//
#include <hip/hip_runtime.h>
#include <hip/hip_bf16.h>
#include <math.h>

#define B_ 4
#define T_ 4096
#define E_ 1024
#define H_ 64
#define NQT 128      // T_/32 q-tiles
#define NCH 4        // passA key chunks (1024 keys each)
#define KCHUNK 1024
#define NCHP 8       // passB chunk slots (512 keys each)
#define KCHB 512
#define TILES 576    // per-batch live causal tiles: sum_qt ((qt>>4)+1)

using bf16x8 = __attribute__((ext_vector_type(8))) short;
using f32x4  = __attribute__((ext_vector_type(4))) float;

__device__ inline short f2bf(float f) {
  __hip_bfloat16 h = __float2bfloat16(f);
  return *reinterpret_cast<short*>(&h);
}
__device__ inline float bf2f(short s) {
  unsigned u = ((unsigned)(unsigned short)s) << 16;
  return __builtin_bit_cast(float, u);
}

// ---------- W transpose+convert: wt[mat*64+n][k] = W[k][n] (bf16) ----------
__global__ __launch_bounds__(256)
void wtconv_kernel(const float* __restrict__ wq, const float* __restrict__ wk,
                   const float* __restrict__ wv, short* __restrict__ wt) {
  const int row = blockIdx.x;          // 0..191
  const int mat = row >> 6, n = row & 63;
  const float* W = (mat == 0) ? wq : (mat == 1) ? wk : wv;
  for (int k = threadIdx.x; k < E_; k += 256)
    wt[(size_t)row * E_ + k] = f2bf(W[(size_t)k * H_ + n]);
}

// ---------- QKV projection: single pass over x ----------
__global__ __launch_bounds__(256)
void proj_kernel(const float* __restrict__ x, const short* __restrict__ wt,
                 short* __restrict__ Qb, short* __restrict__ Kb,
                 short* __restrict__ Vt) {
  const int q0 = blockIdx.x * 32;
  const int t = threadIdx.x;
  const int wave = t >> 6, lane = t & 63, g = lane >> 4, l15 = lane & 15;
  const int qsub = wave >> 1, ch = wave & 1;
  const int arow = q0 + qsub * 16 + l15;
  f32x4 acc[6] = {{0,0,0,0},{0,0,0,0},{0,0,0,0},{0,0,0,0},{0,0,0,0},{0,0,0,0}};
#pragma unroll 2
  for (int k0 = 0; k0 < E_; k0 += 32) {
    const float* xp = x + (size_t)arow * E_ + k0 + 8 * g;
    const float4 x0 = *(const float4*)xp;
    const float4 x1 = *(const float4*)(xp + 4);
    bf16x8 av;
    av[0]=f2bf(x0.x); av[1]=f2bf(x0.y); av[2]=f2bf(x0.z); av[3]=f2bf(x0.w);
    av[4]=f2bf(x1.x); av[5]=f2bf(x1.y); av[6]=f2bf(x1.z); av[7]=f2bf(x1.w);
#pragma unroll
    for (int n = 0; n < 6; ++n) {
      const int ntg = ch * 6 + n;
      const bf16x8 bfr = *(const bf16x8*)&wt[(size_t)(ntg*16 + l15) * E_ + k0 + 8*g];
      acc[n] = __builtin_amdgcn_mfma_f32_16x16x32_bf16(av, bfr, acc[n], 0, 0, 0);
    }
  }
#pragma unroll
  for (int n = 0; n < 6; ++n) {
    const int ntg = ch * 6 + n;
    const int mat = ntg >> 2;
    const int h = (ntg & 3) * 16 + l15;
#pragma unroll
    for (int r = 0; r < 4; ++r) {
      const int q = q0 + qsub * 16 + 4 * g + r;
      const short v = f2bf(acc[n][r]);
      if (mat == 0)      Qb[(size_t)q * H_ + h] = v;
      else if (mat == 1) Kb[(size_t)q * H_ + h] = v;
      else               Vt[((size_t)(q >> 12) * H_ + h) * T_ + (q & (T_ - 1))] = v;
    }
  }
}

// ---------- pass A: partial Z over a 1024-key chunk ----------
__global__ __launch_bounds__(256)
void passA_kernel(const short* __restrict__ Qb, const short* __restrict__ Kb,
                  float* __restrict__ Zp) {
  __shared__ float partial[4][32];
  const int qt = blockIdx.x, c = blockIdx.y, b = blockIdx.z;
  const int q0 = qt * 32;
  const int t = threadIdx.x;
  const int wave = t >> 6, lane = t & 63, g = lane >> 4, l15 = lane & 15;
  const short* Qp = Qb + (size_t)b * T_ * H_;
  const short* Kp = Kb + (size_t)b * T_ * H_;
  bf16x8 aq[2][2];
#pragma unroll
  for (int qs = 0; qs < 2; ++qs)
#pragma unroll
    for (int h = 0; h < 2; ++h)
      aq[qs][h] = *(const bf16x8*)&Qp[(size_t)(q0 + qs*16 + l15) * H_ + h*32 + 8*g];
  float z[2][4] = {{0,0,0,0},{0,0,0,0}};
  const int kendc = c * KCHUNK + KCHUNK;
#pragma unroll 4
  for (int kt = c * KCHUNK + wave * 16; kt < kendc; kt += 64) {
    const bf16x8 bk0 = *(const bf16x8*)&Kp[(size_t)(kt + l15) * H_ + 8*g];
    const bf16x8 bk1 = *(const bf16x8*)&Kp[(size_t)(kt + l15) * H_ + 32 + 8*g];
#pragma unroll
    for (int qs = 0; qs < 2; ++qs) {
      f32x4 cc = {0,0,0,0};
      cc = __builtin_amdgcn_mfma_f32_16x16x32_bf16(aq[qs][0], bk0, cc, 0,0,0);
      cc = __builtin_amdgcn_mfma_f32_16x16x32_bf16(aq[qs][1], bk1, cc, 0,0,0);
#pragma unroll
      for (int r = 0; r < 4; ++r) z[qs][r] += __expf(cc[r] * 0.125f);
    }
  }
#pragma unroll
  for (int qs = 0; qs < 2; ++qs)
#pragma unroll
    for (int r = 0; r < 4; ++r) {
      float v = z[qs][r];
      v += __shfl_xor(v, 1); v += __shfl_xor(v, 2);
      v += __shfl_xor(v, 4); v += __shfl_xor(v, 8);
      z[qs][r] = v;
    }
  if (l15 == 0) {
#pragma unroll
    for (int qs = 0; qs < 2; ++qs)
#pragma unroll
      for (int r = 0; r < 4; ++r)
        partial[wave][qs * 16 + 4 * g + r] = z[qs][r];
  }
  __syncthreads();
  if (t < 32)
    Zp[((size_t)(b * NQT + qt) * NCH + c) * 32 + t] =
        partial[0][t] + partial[1][t] + partial[2][t] + partial[3][t];
}

// ---------- pass B: all-register swapped-MFMA causal chunk partial ----------
// Scores computed as C[key][q] (A = permuted K rows, B = Q). Key permutation
// sigma(l15) = (l15>>2)*8 + (l15&3) makes lane (l15,g) reg r hold key 8g+r
// (tile0) / 8g+4+r (tile1), i.e. exactly the B-fragment slots of the K=32 PV
// MFMA after bf16 conversion. No LDS round-trip, no cross-lane moves.
__global__ __launch_bounds__(256)
void passB_kernel(const short* __restrict__ Qb, const short* __restrict__ Kb,
                  const short* __restrict__ Vt, const float* __restrict__ Zp,
                  short* __restrict__ po, float* __restrict__ pws) {
  __shared__ float comb[2][16][68];
  __shared__ float wsum_lds[2][16];
  const int b = blockIdx.y;
  const int f = TILES - 1 - blockIdx.x;    // ascending live-tile index
  int a = 0;
#pragma unroll
  for (int aa = 1; aa <= 7; ++aa) a += (f >= 8 * aa * (aa + 1)) ? 1 : 0;
  const int rem = f - 8 * a * (a + 1);
  const int r_ = rem / (a + 1);
  const int c = rem - r_ * (a + 1);
  const int qt = (a << 4) + r_;
  const int q0 = qt * 32;
  const int c0 = c * KCHB;
  const int kend = min(c0 + KCHB, q0 + 32);

  const int t = threadIdx.x;
  const int wave = t >> 6, lane = t & 63, g = lane >> 4, l15 = lane & 15;
  const int qsub = wave & 1;
  const int qglob = q0 + qsub * 16 + l15;
  const short* Qp = Qb + (size_t)b * T_ * H_;
  const short* Kp = Kb + (size_t)b * T_ * H_;
  const short* Vp = Vt + (size_t)b * H_ * T_;

  // Q as B-fragment: lane (l15,g) holds Q[q=qglob][h = 8g..8g+7] (+32)
  const bf16x8 aq0 = *(const bf16x8*)&Qp[(size_t)qglob * H_ + 8 * g];
  const bf16x8 aq1 = *(const bf16x8*)&Qp[(size_t)qglob * H_ + 32 + 8 * g];

  const size_t zbase = (size_t)(b * NQT + qt) * NCH;
  float zt = 0.f;
#pragma unroll
  for (int cc = 0; cc < NCH; ++cc) zt += Zp[(zbase + cc) * 32 + qsub * 16 + l15];
  const float zinv = 1.0f / zt;

  f32x4 o[4] = {{0,0,0,0},{0,0,0,0},{0,0,0,0},{0,0,0,0}};
  float ws = 0.f;
  const int krow = ((l15 >> 2) << 3) + (l15 & 3);   // sigma(l15)

#pragma unroll 2
  for (int kt = c0 + (wave >> 1) * 32; kt < kend; kt += 64) {
    const short* kr0 = &Kp[(size_t)(kt + krow) * H_];
    const bf16x8 ak00 = *(const bf16x8*)(kr0 + 8 * g);
    const bf16x8 ak01 = *(const bf16x8*)(kr0 + 32 + 8 * g);
    const bf16x8 ak10 = *(const bf16x8*)(kr0 + 4 * H_ + 8 * g);
    const bf16x8 ak11 = *(const bf16x8*)(kr0 + 4 * H_ + 32 + 8 * g);
    f32x4 s0 = {0,0,0,0}, s1 = {0,0,0,0};
    s0 = __builtin_amdgcn_mfma_f32_16x16x32_bf16(ak00, aq0, s0, 0,0,0);
    s0 = __builtin_amdgcn_mfma_f32_16x16x32_bf16(ak01, aq1, s0, 0,0,0);
    s1 = __builtin_amdgcn_mfma_f32_16x16x32_bf16(ak10, aq0, s1, 0,0,0);
    s1 = __builtin_amdgcn_mfma_f32_16x16x32_bf16(ak11, aq1, s1, 0,0,0);
    bf16x8 wb;
#pragma unroll
    for (int r = 0; r < 4; ++r) {
      const int key0 = kt + 8 * g + r;
      const float p0 = __expf(s0[r] * 0.125f) * zinv;
      const float w0 = (key0 <= qglob) ? __expf(p0) : 0.0f;
      ws += w0;
      wb[r] = f2bf(w0);
      const float p1 = __expf(s1[r] * 0.125f) * zinv;
      const float w1 = (key0 + 4 <= qglob) ? __expf(p1) : 0.0f;
      ws += w1;
      wb[4 + r] = f2bf(w1);
    }
#pragma unroll
    for (int nt = 0; nt < 4; ++nt) {
      const bf16x8 av = *(const bf16x8*)&Vp[(size_t)(nt*16 + l15) * T_ + kt + 8*g];
      o[nt] = __builtin_amdgcn_mfma_f32_16x16x32_bf16(av, wb, o[nt], 0,0,0);
    }
  }

  // reduce ws across the 4 g-groups (lane bits 4,5)
  ws += __shfl_xor(ws, 16);
  ws += __shfl_xor(ws, 32);

  // combine the two key-half wave-pairs
  if (wave >> 1) {
#pragma unroll
    for (int nt = 0; nt < 4; ++nt)
#pragma unroll
      for (int r = 0; r < 4; ++r)
        comb[qsub][l15][nt * 16 + 4 * g + r] = o[nt][r];
    if (lane < 16) wsum_lds[qsub][lane] = ws;
  }
  __syncthreads();
  if (!(wave >> 1)) {
    const size_t idx = (size_t)(b * NQT + qt) * NCHP + c;
    const size_t row = idx * 32 + qsub * 16 + l15;
#pragma unroll
    for (int nt = 0; nt < 4; ++nt) {
      short4 v;
      v.x = f2bf(o[nt][0] + comb[qsub][l15][nt * 16 + 4 * g + 0]);
      v.y = f2bf(o[nt][1] + comb[qsub][l15][nt * 16 + 4 * g + 1]);
      v.z = f2bf(o[nt][2] + comb[qsub][l15][nt * 16 + 4 * g + 2]);
      v.w = f2bf(o[nt][3] + comb[qsub][l15][nt * 16 + 4 * g + 3]);
      *(short4*)&po[row * 64 + nt * 16 + 4 * g] = v;
    }
    if (lane < 16) pws[idx * 32 + qsub * 16 + lane] = ws + wsum_lds[qsub][lane];
  }
}

// ---------- combine: out = sum_c po / sum_c pws ----------
__global__ __launch_bounds__(256)
void combine_kernel(const short* __restrict__ po, const float* __restrict__ pws,
                    float* __restrict__ out) {
  const int qt = blockIdx.x, b = blockIdx.y;
  const int nc = (qt >> 4) + 1;
  const size_t base = (size_t)(b * NQT + qt) * NCHP;
  for (int e = threadIdx.x; e < 512; e += 256) {
    const int q = e >> 4, d4 = e & 15;
    float ax = 0.f, ay = 0.f, az = 0.f, aw = 0.f, wsr = 0.f;
    for (int cc = 0; cc < nc; ++cc) {
      const short4 v = *(const short4*)&po[((base + cc) * 32 + q) * 64 + d4 * 4];
      ax += bf2f(v.x); ay += bf2f(v.y); az += bf2f(v.z); aw += bf2f(v.w);
      wsr += pws[(base + cc) * 32 + q];
    }
    const float inv = 1.0f / wsr;
    float4 rv = make_float4(ax * inv, ay * inv, az * inv, aw * inv);
    *(float4*)&out[((size_t)(b * T_ + qt * 32 + q)) * H_ + d4 * 4] = rv;
  }
}

extern "C" void kernel_launch(void* const* d_in, const int* in_sizes, int n_in,
                              void* d_out, int out_size, void* d_ws, size_t ws_size,
                              hipStream_t stream) {
  (void)in_sizes; (void)n_in; (void)out_size; (void)ws_size;
  const float* x  = (const float*)d_in[0];
  const float* wq = (const float*)d_in[1];
  const float* wk = (const float*)d_in[2];
  const float* wv = (const float*)d_in[3];

  char* ws = (char*)d_ws;
  short* wt  = (short*)(ws);                       // 384 KB
  short* Qb  = (short*)(ws + 0x0060000);           // 2 MB
  short* Kb  = (short*)(ws + 0x0260000);           // 2 MB
  short* Vt  = (short*)(ws + 0x0460000);           // 2 MB
  float* Zp  = (float*)(ws + 0x0660000);           // 256 KB
  float* pws = (float*)(ws + 0x06A0000);           // 512 KB
  short* po  = (short*)(ws + 0x0720000);           // 16 MB bf16
  float* outp = (float*)d_out;

  wtconv_kernel<<<192, 256, 0, stream>>>(wq, wk, wv, wt);
  proj_kernel<<<(B_ * T_) / 32, 256, 0, stream>>>(x, wt, Qb, Kb, Vt);
  passA_kernel<<<dim3(NQT, NCH, B_), 256, 0, stream>>>(Qb, Kb, Zp);
  passB_kernel<<<dim3(TILES, B_), 256, 0, stream>>>(Qb, Kb, Vt, Zp, po, pws);
  combine_kernel<<<dim3(NQT, B_), 256, 0, stream>>>(po, pws, outp);
}